// Round 1
// baseline (71.828 us; speedup 1.0000x reference)
//
#include <hip/hip_runtime.h>

#define BINS 64
// layout of d_ws (uint32): [2 tensors][3 channels][64 bins] = 384 counters
#define HIST_COUNTERS 384
#define WAVES_PER_BLOCK 4
#define BLOCK 256

__global__ __launch_bounds__(BLOCK) void hist_kernel(
    const float4* __restrict__ pred4,
    const float4* __restrict__ targ4,
    unsigned int* __restrict__ ghist,
    long long nvec)  // number of float4 vectors per tensor
{
    // per-wave replicated histograms: [wave][tensor][ch][bin]
    __shared__ unsigned int lhist[WAVES_PER_BLOCK * HIST_COUNTERS];

    const int tid  = threadIdx.x;
    const int wave = tid >> 6;

    for (int j = tid; j < WAVES_PER_BLOCK * HIST_COUNTERS; j += BLOCK)
        lhist[j] = 0u;
    __syncthreads();

    unsigned int* wh = &lhist[wave * HIST_COUNTERS];

    const long long stride = (long long)gridDim.x * BLOCK;
    for (long long v = (long long)blockIdx.x * BLOCK + tid; v < nvec; v += stride) {
        // element index = 4*v; channel = ((4v) >> 18) % 3 = (v >> 16) % 3
        const int ch = (int)((v >> 16) % 3);
        unsigned int* hp = wh + ch * BINS;        // pred hist for this channel
        unsigned int* ht = hp + 3 * BINS;         // target hist (offset 192)

        float4 p = pred4[v];
        float4 t = targ4[v];

        // torch.histc semantics: in-range [0,1]; bin = clip(floor(x*64),0,63)
        #define DO_BIN(x, h)                                                \
            do {                                                            \
                float _x = (x);                                             \
                if (_x >= 0.0f && _x <= 1.0f) {                             \
                    int _b = (int)(_x * 64.0f);  /* trunc==floor, x>=0 */   \
                    _b = _b > 63 ? 63 : _b;                                 \
                    atomicAdd(&h[_b], 1u);                                  \
                }                                                           \
            } while (0)

        DO_BIN(p.x, hp); DO_BIN(p.y, hp); DO_BIN(p.z, hp); DO_BIN(p.w, hp);
        DO_BIN(t.x, ht); DO_BIN(t.y, ht); DO_BIN(t.z, ht); DO_BIN(t.w, ht);
        #undef DO_BIN
    }

    __syncthreads();

    // flush: sum over the 4 wave replicas, one global atomic per counter
    for (int j = tid; j < HIST_COUNTERS; j += BLOCK) {
        unsigned int s = lhist[j]
                       + lhist[j + HIST_COUNTERS]
                       + lhist[j + 2 * HIST_COUNTERS]
                       + lhist[j + 3 * HIST_COUNTERS];
        if (s) atomicAdd(&ghist[j], s);
    }
}

__global__ void finalize_kernel(const unsigned int* __restrict__ ghist,
                                float* __restrict__ out)
{
    const int lane = threadIdx.x;  // 0..63, one wave
    const float eps = 1e-7f;
    float acc = 0.0f;

    for (int c = 0; c < 3; ++c) {
        float pc = (float)ghist[c * BINS + lane];
        float tc = (float)ghist[3 * BINS + c * BINS + lane];

        // exact fp32 sums: all counts & partial sums are integers < 2^24
        float ps = pc, ts = tc;
        #pragma unroll
        for (int o = 32; o >= 1; o >>= 1) {
            ps += __shfl_xor(ps, o);
            ts += __shfl_xor(ts, o);
        }

        float d = fabsf(pc / (ps + eps) - tc / (ts + eps));
        #pragma unroll
        for (int o = 32; o >= 1; o >>= 1)
            d += __shfl_xor(d, o);

        acc += d / 64.0f;   // mean over bins
    }

    if (lane == 0) out[0] = acc / 3.0f;
}

extern "C" void kernel_launch(void* const* d_in, const int* in_sizes, int n_in,
                              void* d_out, int out_size, void* d_ws, size_t ws_size,
                              hipStream_t stream)
{
    const float* pred = (const float*)d_in[0];
    const float* targ = (const float*)d_in[1];
    float* out = (float*)d_out;
    unsigned int* ghist = (unsigned int*)d_ws;

    const long long n = (long long)in_sizes[0];   // 32*3*512*512 = 25,165,824
    const long long nvec = n >> 2;                // divisible by 4

    hipMemsetAsync(ghist, 0, HIST_COUNTERS * sizeof(unsigned int), stream);

    const int grid = 2048;  // 256 CUs * 8 blocks, grid-stride covers the rest
    hist_kernel<<<grid, BLOCK, 0, stream>>>(
        (const float4*)pred, (const float4*)targ, ghist, nvec);

    finalize_kernel<<<1, 64, 0, stream>>>(ghist, out);
}

// Round 2
// 52.979 us; speedup vs baseline: 1.3558x; 1.3558x over previous
//
#include <hip/hip_runtime.h>

#define BINS 64
// one histogram set = [2 tensors][3 channels][64 bins] = 384 u32 = 1536 B
#define HIST_COUNTERS 384
#define BLOCK 256
#define WAVES_PER_BLOCK 4
#define GRID 2048
#define MAX_REPLICAS 64

__global__ __launch_bounds__(BLOCK) void hist_kernel(
    const float4* __restrict__ pred4,
    const float4* __restrict__ targ4,
    unsigned int* __restrict__ ghist,   // [replicas][384]
    long long nvec,                     // float4 vectors per tensor
    int replicas)
{
    // per-wave replicated LDS histograms: [wave][tensor][ch][bin]
    __shared__ unsigned int lhist[WAVES_PER_BLOCK * HIST_COUNTERS];

    const int tid  = threadIdx.x;
    const int wave = tid >> 6;

    for (int j = tid; j < WAVES_PER_BLOCK * HIST_COUNTERS; j += BLOCK)
        lhist[j] = 0u;
    __syncthreads();

    unsigned int* wh = &lhist[wave * HIST_COUNTERS];

    // torch.histc semantics: in-range [0,1]; bin = clip(floor(x*64),0,63)
    #define DO_BIN(x, h)                                                \
        do {                                                            \
            float _x = (x);                                             \
            if (_x >= 0.0f && _x <= 1.0f) {                             \
                int _b = (int)(_x * 64.0f);  /* trunc==floor, x>=0 */   \
                _b = _b > 63 ? 63 : _b;                                 \
                atomicAdd(&h[_b], 1u);                                  \
            }                                                           \
        } while (0)

    #define DO_VEC(p, t, ch)                                            \
        do {                                                            \
            unsigned int* hp = wh + (ch) * BINS;                        \
            unsigned int* ht = hp + 3 * BINS;                           \
            DO_BIN((p).x, hp); DO_BIN((p).y, hp);                       \
            DO_BIN((p).z, hp); DO_BIN((p).w, hp);                       \
            DO_BIN((t).x, ht); DO_BIN((t).y, ht);                       \
            DO_BIN((t).z, ht); DO_BIN((t).w, ht);                       \
        } while (0)

    const long long stride = (long long)GRID * BLOCK;
    long long v = (long long)blockIdx.x * BLOCK + tid;

    // 2x unroll across grid-stride chunks: issue all 4 loads before any LDS op
    for (; v + stride < nvec; v += 2 * stride) {
        const long long v1 = v + stride;
        float4 p0 = pred4[v];
        float4 t0 = targ4[v];
        float4 p1 = pred4[v1];
        float4 t1 = targ4[v1];
        // element index = 4*v; channel = ((4v) >> 18) % 3 = (v >> 16) % 3
        const int ch0 = (int)((v  >> 16) % 3);
        const int ch1 = (int)((v1 >> 16) % 3);
        DO_VEC(p0, t0, ch0);
        DO_VEC(p1, t1, ch1);
    }
    if (v < nvec) {
        float4 p0 = pred4[v];
        float4 t0 = targ4[v];
        const int ch0 = (int)((v >> 16) % 3);
        DO_VEC(p0, t0, ch0);
    }
    #undef DO_VEC
    #undef DO_BIN

    __syncthreads();

    // flush: sum the 4 wave replicas, one global atomic per counter into
    // this block's replica slot (contention per address = GRID/replicas)
    unsigned int* grep = ghist + (blockIdx.x % replicas) * HIST_COUNTERS;
    for (int j = tid; j < HIST_COUNTERS; j += BLOCK) {
        unsigned int s = lhist[j]
                       + lhist[j + HIST_COUNTERS]
                       + lhist[j + 2 * HIST_COUNTERS]
                       + lhist[j + 3 * HIST_COUNTERS];
        if (s) atomicAdd(&grep[j], s);
    }
}

__global__ __launch_bounds__(HIST_COUNTERS) void finalize_kernel(
    const unsigned int* __restrict__ ghist,
    float* __restrict__ out,
    int replicas)
{
    __shared__ unsigned int sums[HIST_COUNTERS];
    const int tid = threadIdx.x;   // 0..383

    unsigned int s = 0u;
    for (int r = 0; r < replicas; ++r)
        s += ghist[r * HIST_COUNTERS + tid];
    sums[tid] = s;
    __syncthreads();

    if (tid < 64) {
        const int lane = tid;
        const float eps = 1e-7f;
        float acc = 0.0f;

        for (int c = 0; c < 3; ++c) {
            float pc = (float)sums[c * BINS + lane];
            float tc = (float)sums[3 * BINS + c * BINS + lane];

            // exact fp32 sums: all counts & partial sums are integers < 2^24
            float ps = pc, ts = tc;
            #pragma unroll
            for (int o = 32; o >= 1; o >>= 1) {
                ps += __shfl_xor(ps, o);
                ts += __shfl_xor(ts, o);
            }

            float d = fabsf(pc / (ps + eps) - tc / (ts + eps));
            #pragma unroll
            for (int o = 32; o >= 1; o >>= 1)
                d += __shfl_xor(d, o);

            acc += d / 64.0f;   // mean over bins
        }

        if (lane == 0) out[0] = acc / 3.0f;
    }
}

extern "C" void kernel_launch(void* const* d_in, const int* in_sizes, int n_in,
                              void* d_out, int out_size, void* d_ws, size_t ws_size,
                              hipStream_t stream)
{
    const float* pred = (const float*)d_in[0];
    const float* targ = (const float*)d_in[1];
    float* out = (float*)d_out;
    unsigned int* ghist = (unsigned int*)d_ws;

    const long long n = (long long)in_sizes[0];   // 32*3*512*512 = 25,165,824
    const long long nvec = n >> 2;                // divisible by 4

    // as many global-histogram replicas as the workspace allows, up to 64
    int replicas = (int)(ws_size / (HIST_COUNTERS * sizeof(unsigned int)));
    if (replicas > MAX_REPLICAS) replicas = MAX_REPLICAS;
    if (replicas < 1) replicas = 1;

    hipMemsetAsync(ghist, 0,
                   (size_t)replicas * HIST_COUNTERS * sizeof(unsigned int),
                   stream);

    hist_kernel<<<GRID, BLOCK, 0, stream>>>(
        (const float4*)pred, (const float4*)targ, ghist, nvec, replicas);

    finalize_kernel<<<1, HIST_COUNTERS, 0, stream>>>(ghist, out, replicas);
}